// Round 11
// baseline (972.689 us; speedup 1.0000x reference)
//
#include <hip/hip_runtime.h>
#include <hip/hip_bf16.h>
#include <cstdint>

#define DH 128   // hidden dim
#define NB 256   // partition blocks for CSR build
#define NBK 1024 // max buckets (N <= 131072)

typedef __attribute__((ext_vector_type(8))) short short8;
typedef __attribute__((ext_vector_type(4))) float floatx4;
typedef __attribute__((ext_vector_type(2))) float floatx2;

__device__ __forceinline__ float bflo(unsigned u) { return __uint_as_float(u << 16); }
__device__ __forceinline__ float bfhi(unsigned u) { return __uint_as_float(u & 0xffff0000u); }

__device__ __forceinline__ unsigned pk_bf16(float a, float b) {
  return ((unsigned)__bfloat16_as_ushort(__float2bfloat16(b)) << 16)
       | (unsigned)__bfloat16_as_ushort(__float2bfloat16(a));
}

template<int CTRL>
__device__ __forceinline__ float dpp_add(float x) {
  int y = __builtin_amdgcn_update_dpp(0, __float_as_int(x), CTRL, 0xf, 0xf, true);
  return x + __int_as_float(y);
}

// ---------------- scans (generic, for bucket starts) ----------------

__global__ void scan1_kernel(const int* __restrict__ deg, int* __restrict__ off,
                             int* __restrict__ bsum, int n) {
  __shared__ int sh[256];
  int idx = blockIdx.x * 256 + threadIdx.x;
  int v = (idx < n) ? deg[idx] : 0;
  sh[threadIdx.x] = v;
  __syncthreads();
  for (int d = 1; d < 256; d <<= 1) {
    int x = (threadIdx.x >= (unsigned)d) ? sh[threadIdx.x - d] : 0;
    __syncthreads();
    sh[threadIdx.x] += x;
    __syncthreads();
  }
  if (idx < n) off[idx] = sh[threadIdx.x] - v;   // exclusive
  if (threadIdx.x == 255) bsum[blockIdx.x] = sh[255];
}

__global__ void scan2_kernel(int* __restrict__ bsum, int nb) {
  __shared__ int sh[512];
  int t = threadIdx.x;
  int v = (t < nb) ? bsum[t] : 0;
  sh[t] = v;
  __syncthreads();
  for (int d = 1; d < 512; d <<= 1) {
    int x = (t >= (unsigned)d) ? sh[t - d] : 0;
    __syncthreads();
    sh[t] += x;
    __syncthreads();
  }
  if (t < nb) bsum[t] = sh[t] - v;
}

__global__ void scan3_kernel(int* __restrict__ off, const int* __restrict__ bsum, int n) {
  int idx = blockIdx.x * 256 + threadIdx.x;
  if (idx < n) off[idx] += bsum[blockIdx.x];
}

// ---------------- atomic-free CSR build (counting sort by dst>>7) ----------------
// hist layout TRANSPOSED: hist[bucket * NB + blk]

__global__ __launch_bounds__(256)
void csr_p1(const int* __restrict__ dst, int* __restrict__ hist, int E, int chunk) {
  __shared__ int cnt[NBK];
  const int blk = blockIdx.x, tid = threadIdx.x;
  for (int c = tid; c < NBK; c += 256) cnt[c] = 0;
  __syncthreads();
  int base = blk * chunk;
  int end = base + chunk; if (end > E) end = E;
  for (int e = base + tid; e < end; e += 256) atomicAdd(&cnt[dst[e] >> 7], 1);
  __syncthreads();
  for (int c = tid; c < NBK; c += 256) hist[c * NB + blk] = cnt[c];
}

__global__ __launch_bounds__(256)
void csr_p2(int* __restrict__ hist, int* __restrict__ total) {
  int b = blockIdx.x * 4 + (threadIdx.x >> 6);   // bucket
  int lane = threadIdx.x & 63;
  int4 v = *(int4*)&hist[b * NB + lane * 4];
  int s0 = v.x;
  int s1 = s0 + v.y;
  int s2 = s1 + v.z;
  int s3 = s2 + v.w;
  int t = s3;
  for (int d = 1; d < 64; d <<= 1) {
    int y = __shfl_up(t, d);
    if (lane >= d) t += y;
  }
  int excl = t - s3;
  int4 o;
  o.x = excl; o.y = excl + s0; o.z = excl + s1; o.w = excl + s2;
  *(int4*)&hist[b * NB + lane * 4] = o;
  if (lane == 63) total[b] = t;
}

__global__ __launch_bounds__(256)
void csr_p3(const int* __restrict__ src, const int* __restrict__ dst,
            const int* __restrict__ hist, const int* __restrict__ tstart,
            int* __restrict__ part, int E, int chunk) {
  __shared__ int cur[NBK];
  const int blk = blockIdx.x, tid = threadIdx.x;
  for (int c = tid; c < NBK; c += 256) cur[c] = hist[c * NB + blk] + tstart[c];
  __syncthreads();
  int base = blk * chunk;
  int end = base + chunk; if (end > E) end = E;
  for (int e = base + tid; e < end; e += 256) {
    int d = dst[e];
    int b = d >> 7;
    int pos = atomicAdd(&cur[b], 1);     // LDS atomic
    part[pos] = (src[e] << 7) | (d & 127);
  }
}

__global__ __launch_bounds__(256)
void csr_p4(const int* __restrict__ part, const int* __restrict__ tstart,
            const int* __restrict__ total, int* __restrict__ deg,
            int* __restrict__ off, int* __restrict__ csr, int Nn) {
  __shared__ int lcnt[128], lscan[128], lcur[128];
  const int b = blockIdx.x, tid = threadIdx.x;
  const int p0 = tstart[b];
  const int m = total[b];
  if (tid < 128) lcnt[tid] = 0;
  __syncthreads();
  for (int k = tid; k < m; k += 256) atomicAdd(&lcnt[part[p0 + k] & 127], 1);
  __syncthreads();
  if (tid < 128) lscan[tid] = lcnt[tid];
  __syncthreads();
  for (int d = 1; d < 128; d <<= 1) {
    int v = 0;
    if (tid < 128 && tid >= d) v = lscan[tid - d];
    __syncthreads();
    if (tid < 128) lscan[tid] += v;
    __syncthreads();
  }
  if (tid < 128) {
    int ex = lscan[tid] - lcnt[tid];
    lcur[tid] = ex;
    int n = (b << 7) + tid;
    if (n < Nn) { deg[n] = lcnt[tid]; off[n] = p0 + ex; }
  }
  __syncthreads();
  for (int k = tid; k < m; k += 256) {
    int pk = part[p0 + k];
    int pos = p0 + atomicAdd(&lcur[pk & 127], 1);   // LDS atomic
    csr[pos] = pk >> 7;
  }
}

// ---------------- graph segment offsets via binary search (batch sorted) --------

__global__ void goff_kernel(const int* __restrict__ batch, int* __restrict__ goff,
                            int N, int G) {
  int g = blockIdx.x * 256 + threadIdx.x;
  if (g > G) return;
  if (g == G) { goff[G] = N; return; }
  int lo = 0, hi = N;
  while (lo < hi) { int mid = (lo + hi) >> 1; if (batch[mid] < g) lo = mid + 1; else hi = mid; }
  goff[g] = lo;
}

// ---------------- weight pack -> MFMA FRAGMENT ORDER -----------------------------

__global__ __launch_bounds__(256)
void pack_w_kernel(const float* __restrict__ Wq, const float* __restrict__ Wk,
                   const float* __restrict__ Wv, const float* __restrict__ Ws,
                   const float* __restrict__ bq, const float* __restrict__ bk,
                   const float* __restrict__ bv, const float* __restrict__ bs,
                   __hip_bfloat16* __restrict__ WT2, float* __restrict__ bcat) {
  if (blockIdx.x == 64) {
    for (int c = threadIdx.x; c < 512; c += 256) {
      int which = c >> 7, cc = c & 127;
      const float* b = (which == 0) ? bq : (which == 1) ? bk : (which == 2) ? bv : bs;
      bcat[c] = b[cc];
    }
    return;
  }
  __shared__ float tile[32][33];   // [k-row][c-col]
  const int bid = blockIdx.x;
  const int which = bid >> 4, kb = (bid >> 2) & 3, cb = bid & 3;
  const float* W = (which == 0) ? Wq : (which == 1) ? Wk : (which == 2) ? Wv : Ws;
  const int tx = threadIdx.x & 31, ty = threadIdx.x >> 5;   // ty 0..7
#pragma unroll
  for (int r = ty; r < 32; r += 8)
    tile[r][tx] = W[(kb * 32 + r) * 128 + cb * 32 + tx];
  __syncthreads();
  const int t = threadIdx.x;
  const int mt_sel = t >> 7;            // 0..1
  const int s4 = (t & 127) * 4;
  const int l16 = s4 >> 5;
  const int quad = (s4 >> 3) & 3;
  const int j0 = s4 & 7;
  const int cl = mt_sel * 16 + l16;
  const int kr = quad * 8 + j0;
  float f0 = tile[kr + 0][cl];
  float f1 = tile[kr + 1][cl];
  float f2 = tile[kr + 2][cl];
  float f3 = tile[kr + 3][cl];
  const int mt = which * 8 + cb * 2 + mt_sel;
  const int o = mt * 2048 + kb * 512 + l16 * 32 + quad * 8 + j0;
  uint2 w;
  w.x = pk_bf16(f0, f1);
  w.y = pk_bf16(f2, f3);
  *(uint2*)&((unsigned short*)WT2)[o] = w;
}

// ---------------- gemm phase (device): reads As (LDS), writes q/kvp/xr ----------

__device__ __forceinline__ void gemm_phase(
    const short* __restrict__ WT2, const float* __restrict__ bc,
    unsigned int* __restrict__ qout, unsigned int* __restrict__ kvp,
    unsigned int* __restrict__ xrout, int Nn, int row0, int tid,
    const short (*As)[132]) {
  const int w = tid >> 6, lane = tid & 63, quad = lane >> 4, l16 = lane & 15;

  short8 xf[4][4];
#pragma unroll
  for (int nt = 0; nt < 4; ++nt)
#pragma unroll
    for (int kt = 0; kt < 4; ++kt)
      xf[nt][kt] = *(const short8*)&As[nt * 16 + l16][kt * 32 + quad * 8];

  const int fbase = l16 * 32 + quad * 8;

  if (w == 0 || w == 3) {
    unsigned int* outp = (w == 0) ? qout : xrout;
    const int mbase = (w == 0) ? 0 : 24;
#pragma unroll
    for (int i = 0; i < 8; ++i) {
      const int mt = mbase + i;
      short8 af[4];
#pragma unroll
      for (int kt = 0; kt < 4; ++kt)
        af[kt] = *(const short8*)&WT2[mt * 2048 + kt * 512 + fbase];
      float4 bias = *(const float4*)&bc[mt * 16 + quad * 4];
      const int wc = (i * 16 + quad * 4);
#pragma unroll
      for (int nt = 0; nt < 4; ++nt) {
        floatx4 acc = (floatx4){0.f, 0.f, 0.f, 0.f};
#pragma unroll
        for (int kt = 0; kt < 4; ++kt)
          acc = __builtin_amdgcn_mfma_f32_16x16x32_bf16(af[kt], xf[nt][kt], acc, 0, 0, 0);
        int node = row0 + nt * 16 + l16;
        if (node < Nn) {
          uint2 o;
          o.x = pk_bf16(acc[0] + bias.x, acc[1] + bias.y);
          o.y = pk_bf16(acc[2] + bias.z, acc[3] + bias.w);
          *(uint2*)&outp[(size_t)node * 64 + (wc >> 1)] = o;
        }
      }
    }
  } else {
    const int kb = 8 + (w - 1) * 4;
    const int vb = 16 + (w - 1) * 4;
#pragma unroll
    for (int i = 0; i < 4; ++i) {
      const int mk = kb + i, mv = vb + i;
      short8 afk[4], afv[4];
#pragma unroll
      for (int kt = 0; kt < 4; ++kt) {
        afk[kt] = *(const short8*)&WT2[mk * 2048 + kt * 512 + fbase];
        afv[kt] = *(const short8*)&WT2[mv * 2048 + kt * 512 + fbase];
      }
      float4 bk4 = *(const float4*)&bc[mk * 16 + quad * 4];
      float4 bv4 = *(const float4*)&bc[mv * 16 + quad * 4];
      const int krel = (w - 1) * 64 + i * 16 + quad * 4;
#pragma unroll
      for (int nt = 0; nt < 4; ++nt) {
        floatx4 ak = (floatx4){0.f, 0.f, 0.f, 0.f};
        floatx4 av = (floatx4){0.f, 0.f, 0.f, 0.f};
#pragma unroll
        for (int kt = 0; kt < 4; ++kt) {
          ak = __builtin_amdgcn_mfma_f32_16x16x32_bf16(afk[kt], xf[nt][kt], ak, 0, 0, 0);
          av = __builtin_amdgcn_mfma_f32_16x16x32_bf16(afv[kt], xf[nt][kt], av, 0, 0, 0);
        }
        int node = row0 + nt * 16 + l16;
        if (node < Nn) {
          int d0 = __builtin_amdgcn_cvt_pk_fp8_f32(ak[0] + bk4.x, ak[1] + bk4.y, 0, false);
          d0 = __builtin_amdgcn_cvt_pk_fp8_f32(av[0] + bv4.x, av[1] + bv4.y, d0, true);
          int d1 = __builtin_amdgcn_cvt_pk_fp8_f32(ak[2] + bk4.z, ak[3] + bk4.w, 0, false);
          d1 = __builtin_amdgcn_cvt_pk_fp8_f32(av[2] + bv4.z, av[3] + bv4.w, d1, true);
          uint2 o; o.x = (unsigned)d0; o.y = (unsigned)d1;
          *(uint2*)&kvp[(size_t)node * 64 + (krel >> 1)] = o;
        }
      }
    }
  }
}

// ---------------- attn per node (device): R10's 32-lane routine ------------------
// returns packed h (4 feats) valid in lanes g==0

__device__ __forceinline__ uint2 attn_node(
    int i, int j, int g,
    const uint2* __restrict__ qbuf, const uint2* __restrict__ kvp2,
    const uint2* __restrict__ xr2, const int* __restrict__ off,
    const int* __restrict__ deg, const int* __restrict__ csr,
    const float* __restrict__ Wb) {
  const float QS = 0.17677669529663687f * 1.4426950408889634f;  // 1/sqrt(32)*log2e
  uint2 qw = qbuf[(size_t)i * 32 + j];
  float q0 = bflo(qw.x) * QS, q1 = bfhi(qw.x) * QS;
  float q2 = bflo(qw.y) * QS, q3 = bfhi(qw.y) * QS;

  const int e0 = off[i];
  const int dg = deg[i];

  float denA = 0.f, aA0 = 0.f, aA1 = 0.f, aA2 = 0.f, aA3 = 0.f;
  float denB = 0.f, aB0 = 0.f, aB1 = 0.f, aB2 = 0.f, aB3 = 0.f;

  auto pair = [&](int s0, int s1, float& den, float& a0, float& a1, float& a2, float& a3) {
    int s = g ? s1 : s0;
    uint2 kv = kvp2[(unsigned)((s << 5) | j)];
    floatx2 k01 = __builtin_amdgcn_cvt_pk_f32_fp8((int)kv.x, false);
    floatx2 v01 = __builtin_amdgcn_cvt_pk_f32_fp8((int)kv.x, true);
    floatx2 k23 = __builtin_amdgcn_cvt_pk_f32_fp8((int)kv.y, false);
    floatx2 v23 = __builtin_amdgcn_cvt_pk_f32_fp8((int)kv.y, true);
    float d = q0 * k01.x + q1 * k01.y + q2 * k23.x + q3 * k23.y;
    d = dpp_add<0xB1>(d);        // quad_perm xor1
    d = dpp_add<0x4E>(d);        // quad_perm xor2
    d += __shfl_xor(d, 4);
    float p = exp2f(d);
    den += p;
    a0 += p * v01.x; a1 += p * v01.y; a2 += p * v23.x; a3 += p * v23.y;
  };

  const int nPair = dg >> 1;
  int e = e0;
  int it = 0;
  for (; it + 1 < nPair; it += 2) {
    int s0 = csr[e], s1 = csr[e + 1], s2 = csr[e + 2], s3 = csr[e + 3];
    pair(s0, s1, denA, aA0, aA1, aA2, aA3);
    pair(s2, s3, denB, aB0, aB1, aB2, aB3);
    e += 4;
  }
  if (it < nPair) {
    int s0 = csr[e], s1 = csr[e + 1];
    pair(s0, s1, denA, aA0, aA1, aA2, aA3);
    e += 2;
  }
  if (dg & 1) {
    int s = csr[e];
    uint2 kv = kvp2[(unsigned)((s << 5) | j)];
    floatx2 k01 = __builtin_amdgcn_cvt_pk_f32_fp8((int)kv.x, false);
    floatx2 v01 = __builtin_amdgcn_cvt_pk_f32_fp8((int)kv.x, true);
    floatx2 k23 = __builtin_amdgcn_cvt_pk_f32_fp8((int)kv.y, false);
    floatx2 v23 = __builtin_amdgcn_cvt_pk_f32_fp8((int)kv.y, true);
    float d = q0 * k01.x + q1 * k01.y + q2 * k23.x + q3 * k23.y;
    d = dpp_add<0xB1>(d);
    d = dpp_add<0x4E>(d);
    d += __shfl_xor(d, 4);
    float p = (g == 0) ? exp2f(d) : 0.f;
    denB += p;
    aB0 += p * v01.x; aB1 += p * v01.y; aB2 += p * v23.x; aB3 += p * v23.y;
  }

  float den = denA + denB;
  float a0 = aA0 + aB0, a1 = aA1 + aB1, a2 = aA2 + aB2, a3 = aA3 + aB3;
  den += __shfl_xor(den, 32);
  a0 += __shfl_xor(a0, 32);
  a1 += __shfl_xor(a1, 32);
  a2 += __shfl_xor(a2, 32);
  a3 += __shfl_xor(a3, 32);
  float inv = 1.f / (den + 1e-16f);
  float o0 = a0 * inv, o1 = a1 * inv, o2 = a2 * inv, o3 = a3 * inv;

  uint2 xw = xr2[(size_t)i * 32 + j];
  float xr0 = bflo(xw.x), xr1 = bfhi(xw.x);
  float xr2v = bflo(xw.y), xr3 = bfhi(xw.y);

  float4 wo = *(const float4*)&Wb[4 * j];
  float4 wx = *(const float4*)&Wb[128 + 4 * j];
  float4 wd = *(const float4*)&Wb[256 + 4 * j];
  float c = o0 * wo.x + o1 * wo.y + o2 * wo.z + o3 * wo.w
          + xr0 * wx.x + xr1 * wx.y + xr2v * wx.z + xr3 * wx.w
          + (o0 - xr0) * wd.x + (o1 - xr1) * wd.y + (o2 - xr2v) * wd.z + (o3 - xr3) * wd.w;
  c += __shfl_xor(c, 1);
  c += __shfl_xor(c, 2);
  c += __shfl_xor(c, 4);
  c += __shfl_xor(c, 8);
  c += __shfl_xor(c, 16);
  float beta = 1.f / (1.f + __expf(-c));

  float h0 = fmaxf(beta * xr0 + (1.f - beta) * o0, 0.f);
  float h1 = fmaxf(beta * xr1 + (1.f - beta) * o1, 0.f);
  float h2 = fmaxf(beta * xr2v + (1.f - beta) * o2, 0.f);
  float h3 = fmaxf(beta * xr3 + (1.f - beta) * o3, 0.f);
  uint2 hw;
  hw.x = pk_bf16(h0, h1);
  hw.y = pk_bf16(h2, h3);
  return hw;
}

// ---------------- gemm0: stage from fp32 x, then gemm phase ----------------------

__global__ __launch_bounds__(256)
void gemm0_kernel(const float* __restrict__ Xf, const short* __restrict__ WT2,
                  const float* __restrict__ bc,
                  unsigned int* __restrict__ qout, unsigned int* __restrict__ kvp,
                  unsigned int* __restrict__ xrout, int Nn) {
  __shared__ short As[64][132];
  const int row0 = blockIdx.x * 64;
  const int tid = threadIdx.x;
#pragma unroll
  for (int p = 0; p < 8; ++p) {
    int chunk = p * 256 + tid;          // 0..2047
    int r = chunk >> 5;                 // 64 rows
    int c4 = (chunk & 31) * 4;          // 0..124
    int row = row0 + r; if (row >= Nn) row = Nn - 1;
    float4 f = *(const float4*)&Xf[(size_t)row * 128 + c4];
    uint2 pk;
    pk.x = pk_bf16(f.x, f.y);
    pk.y = pk_bf16(f.z, f.w);
    *(uint2*)&As[r][c4] = pk;
  }
  __syncthreads();
  gemm_phase(WT2, bc, qout, kvp, xrout, Nn, row0, tid, As);
}

// ---------------- fused: attn layer l -> LDS h -> gemm layer l+1 -----------------

__global__ __launch_bounds__(256)
void attn_gemm_kernel(const uint2* __restrict__ qb, const uint2* __restrict__ kvpl,
                      const uint2* __restrict__ xrl, const int* __restrict__ off,
                      const int* __restrict__ deg, const int* __restrict__ csr,
                      const float* __restrict__ Wb,
                      const short* __restrict__ WT2n, const float* __restrict__ bcn,
                      unsigned int* __restrict__ qo, unsigned int* __restrict__ kvpn,
                      unsigned int* __restrict__ xro, int Nn) {
  __shared__ short As[64][132];
  const int tid = threadIdx.x;
  const int row0 = blockIdx.x * 64;
  const int w = __builtin_amdgcn_readfirstlane(tid >> 6);
  const int l = tid & 63;
  const int j = l & 31, g = l >> 5;

  for (int r = 0; r < 16; ++r) {
    int i = row0 + w * 16 + r;
    uint2 hw; hw.x = 0u; hw.y = 0u;
    if (i < Nn) hw = attn_node(i, j, g, qb, kvpl, xrl, off, deg, csr, Wb);
    if (g == 0) *(uint2*)&As[w * 16 + r][4 * j] = hw;
  }
  __syncthreads();
  gemm_phase(WT2n, bcn, qo, kvpn, xro, Nn, row0, tid, As);
}

// ---------------- final attn (layer 3): writes h in place over q -----------------

__global__ __launch_bounds__(256)
void attn_final_kernel(unsigned int* __restrict__ q_h, const uint2* __restrict__ kvp2,
                       const uint2* __restrict__ xr2, const int* __restrict__ off,
                       const int* __restrict__ deg, const int* __restrict__ csr,
                       const float* __restrict__ Wb, int Nn) {
  int wv = __builtin_amdgcn_readfirstlane(threadIdx.x >> 6);
  int i = blockIdx.x * 4 + wv;
  if (i >= Nn) return;
  const int l = threadIdx.x & 63;
  const int j = l & 31, g = l >> 5;
  uint2 hw = attn_node(i, j, g, (const uint2*)q_h, kvp2, xr2, off, deg, csr, Wb);
  if (g == 0) ((uint2*)q_h)[(size_t)i * 32 + j] = hw;
}

// ---------------- fused mean-pool + MLP ----------------

__global__ __launch_bounds__(128)
void poolmlp_kernel(const unsigned short* __restrict__ h, const int* __restrict__ goff,
                    const float* __restrict__ W1, const float* __restrict__ b1,
                    const float* __restrict__ W2, const float* __restrict__ b2,
                    const float* __restrict__ W3, const float* __restrict__ b3,
                    float* __restrict__ out) {
  int g = blockIdx.x;
  int t = threadIdx.x;
  int n0 = goff[g], cnt = goff[g + 1] - n0;
  float s = 0.f;
  for (int n = n0; n < n0 + cnt; ++n) s += bflo(h[(size_t)n * 128 + t]);
  __shared__ float gv[128];
  __shared__ float t1[64];
  __shared__ float t2[32];
  gv[t] = s / fmaxf((float)cnt, 1.0f);
  __syncthreads();
  if (t < 64) {
    float a = b1[t];
    for (int k = 0; k < 128; ++k) a += gv[k] * W1[k * 64 + t];
    t1[t] = fmaxf(a, 0.f);
  }
  __syncthreads();
  if (t < 32) {
    float a = b2[t];
    for (int k = 0; k < 64; ++k) a += t1[k] * W2[k * 32 + t];
    t2[t] = fmaxf(a, 0.f);
  }
  __syncthreads();
  if (t == 0) {
    float a = b3[0];
    for (int k = 0; k < 32; ++k) a += t2[k] * W3[k];
    out[g] = 1.f / (1.f + __expf(-a));
  }
}

// ---------------- launch ----------------

extern "C" void kernel_launch(void* const* d_in, const int* in_sizes, int n_in,
                              void* d_out, int out_size, void* d_ws, size_t ws_size,
                              hipStream_t stream) {
  const float* x = (const float*)d_in[0];
  const int* edge_index = (const int*)d_in[1];
  const int* batch = (const int*)d_in[2];
  const int N = in_sizes[0] / DH;
  const int E = in_sizes[1] / 2;
  const int G = out_size;
  const int* src = edge_index;
  const int* dst = edge_index + E;

  const float* in_Wq = (const float*)d_in[3];
  const float* in_bq = (const float*)d_in[4];
  const float* in_Wk = (const float*)d_in[5];
  const float* in_bk = (const float*)d_in[6];
  const float* in_Wv = (const float*)d_in[7];
  const float* in_bv = (const float*)d_in[8];
  const float* in_Ws = (const float*)d_in[9];
  const float* in_bs = (const float*)d_in[10];
  const float* in_Wbeta = (const float*)d_in[11];
  const float* blk_Wq = (const float*)d_in[12];
  const float* blk_bq = (const float*)d_in[13];
  const float* blk_Wk = (const float*)d_in[14];
  const float* blk_bk = (const float*)d_in[15];
  const float* blk_Wv = (const float*)d_in[16];
  const float* blk_bv = (const float*)d_in[17];
  const float* blk_Ws = (const float*)d_in[18];
  const float* blk_bs = (const float*)d_in[19];
  const float* blk_Wbeta = (const float*)d_in[20];

  // workspace carve (256B aligned)
  char* p = (char*)d_ws;
  auto take = [&](size_t bytes) { char* r = p; p += (bytes + 255) & ~(size_t)255; return r; };
  unsigned* qA = (unsigned*)take((size_t)N * DH * 2);
  unsigned* qB = (unsigned*)take((size_t)N * DH * 2);
  unsigned char* kvpA = (unsigned char*)take((size_t)N * 256);
  unsigned char* kvpB = (unsigned char*)take((size_t)N * 256);
  unsigned* xrA = (unsigned*)take((size_t)N * DH * 2);
  unsigned* xrB = (unsigned*)take((size_t)N * DH * 2);
  __hip_bfloat16* WT2 = (__hip_bfloat16*)take((size_t)4 * 512 * DH * 2);
  float* bcat = (float*)take((size_t)4 * 512 * 4);
  int* deg    = (int*)take((size_t)N * 4);
  int* off    = (int*)take((size_t)N * 4);
  int* csr    = (int*)take((size_t)E * 4);
  int* part   = (int*)take((size_t)E * 4);
  int* hist   = (int*)take((size_t)NB * NBK * 4);
  int* total  = (int*)take(NBK * 4);
  int* tstart = (int*)take(NBK * 4);
  int* bsumP  = (int*)take(512 * 4);
  int* goff   = (int*)take((size_t)(G + 1) * 4);
  (void)n_in;
  if ((size_t)(p - (char*)d_ws) > ws_size) return;

  const int NBUCK = (N + 127) >> 7;
  const int chunk = (E + NB - 1) / NB;
  const int NGB = (N + 63) / 64;

  // ---- atomic-free CSR build ----
  csr_p1<<<NB, 256, 0, stream>>>(dst, hist, E, chunk);
  csr_p2<<<NBK / 4, 256, 0, stream>>>(hist, total);
  scan1_kernel<<<NBK / 256, 256, 0, stream>>>(total, tstart, bsumP, NBK);
  scan2_kernel<<<1, 512, 0, stream>>>(bsumP, NBK / 256);
  scan3_kernel<<<NBK / 256, 256, 0, stream>>>(tstart, bsumP, NBK);
  csr_p3<<<NB, 256, 0, stream>>>(src, dst, hist, tstart, part, E, chunk);
  csr_p4<<<NBUCK, 256, 0, stream>>>(part, tstart, total, deg, off, csr, N);

  // ---- graph segment offsets (batch sorted) ----
  goff_kernel<<<(G + 256) / 256, 256, 0, stream>>>(batch, goff, N, G);

  // ---- pack all 4 layers' weights ----
  for (int l = 0; l < 4; ++l) {
    const float *Wq, *Wk, *Wv, *Ws, *bq, *bk, *bv, *bs;
    if (l == 0) {
      Wq = in_Wq; Wk = in_Wk; Wv = in_Wv; Ws = in_Ws;
      bq = in_bq; bk = in_bk; bv = in_bv; bs = in_bs;
    } else {
      int m = l - 1;
      Wq = blk_Wq + (size_t)m * DH * DH; Wk = blk_Wk + (size_t)m * DH * DH;
      Wv = blk_Wv + (size_t)m * DH * DH; Ws = blk_Ws + (size_t)m * DH * DH;
      bq = blk_bq + (size_t)m * DH; bk = blk_bk + (size_t)m * DH;
      bv = blk_bv + (size_t)m * DH; bs = blk_bs + (size_t)m * DH;
    }
    pack_w_kernel<<<65, 256, 0, stream>>>(Wq, Wk, Wv, Ws, bq, bk, bv, bs,
                                          WT2 + (size_t)l * 512 * DH, bcat + l * 512);
  }

  const float* Wb0 = in_Wbeta;
  const float* Wb1 = blk_Wbeta;
  const float* Wb2 = blk_Wbeta + 384;
  const float* Wb3 = blk_Wbeta + 768;
  const short* W0 = (const short*)WT2;
  const short* W1 = (const short*)(WT2 + (size_t)1 * 512 * DH);
  const short* W2 = (const short*)(WT2 + (size_t)2 * 512 * DH);
  const short* W3 = (const short*)(WT2 + (size_t)3 * 512 * DH);

  // layer 0 gemm (from fp32 x)
  gemm0_kernel<<<NGB, 256, 0, stream>>>(x, W0, bcat, qA, (unsigned*)kvpA, xrA, N);
  // fused attn_l + gemm_{l+1}
  attn_gemm_kernel<<<NGB, 256, 0, stream>>>((const uint2*)qA, (const uint2*)kvpA,
      (const uint2*)xrA, off, deg, csr, Wb0, W1, bcat + 512,
      qB, (unsigned*)kvpB, xrB, N);
  attn_gemm_kernel<<<NGB, 256, 0, stream>>>((const uint2*)qB, (const uint2*)kvpB,
      (const uint2*)xrB, off, deg, csr, Wb1, W2, bcat + 1024,
      qA, (unsigned*)kvpA, xrA, N);
  attn_gemm_kernel<<<NGB, 256, 0, stream>>>((const uint2*)qA, (const uint2*)kvpA,
      (const uint2*)xrA, off, deg, csr, Wb2, W3, bcat + 1536,
      qB, (unsigned*)kvpB, xrB, N);
  // final attn (layer 3) -> h in place over qB
  attn_final_kernel<<<(N + 3) / 4, 256, 0, stream>>>(qB, (const uint2*)kvpB,
      (const uint2*)xrB, off, deg, csr, Wb3, N);

  poolmlp_kernel<<<G, 128, 0, stream>>>((const unsigned short*)qB, goff,
      (const float*)d_in[21], (const float*)d_in[22],
      (const float*)d_in[23], (const float*)d_in[24],
      (const float*)d_in[25], (const float*)d_in[26],
      (float*)d_out);
}

// Round 12
// 720.852 us; speedup vs baseline: 1.3494x; 1.3494x over previous
//
#include <hip/hip_runtime.h>
#include <hip/hip_bf16.h>
#include <cstdint>

#define DH 128   // hidden dim
#define NB 256   // partition blocks for CSR build
#define NBK 1024 // max buckets (N <= 131072)

typedef __attribute__((ext_vector_type(8))) short short8;
typedef __attribute__((ext_vector_type(4))) float floatx4;
typedef __attribute__((ext_vector_type(2))) float floatx2;

__device__ __forceinline__ float bflo(unsigned u) { return __uint_as_float(u << 16); }
__device__ __forceinline__ float bfhi(unsigned u) { return __uint_as_float(u & 0xffff0000u); }

__device__ __forceinline__ unsigned pk_bf16(float a, float b) {
  return ((unsigned)__bfloat16_as_ushort(__float2bfloat16(b)) << 16)
       | (unsigned)__bfloat16_as_ushort(__float2bfloat16(a));
}

template<int CTRL>
__device__ __forceinline__ float dpp_add(float x) {
  int y = __builtin_amdgcn_update_dpp(0, __float_as_int(x), CTRL, 0xf, 0xf, true);
  return x + __int_as_float(y);
}

// ---------------- fp32 -> bf16 convert ----------------

__global__ void cvt_bf16(const float* __restrict__ x, __hip_bfloat16* __restrict__ o, int n) {
  int i = blockIdx.x * 256 + threadIdx.x;
  if (i < n) o[i] = __float2bfloat16(x[i]);
}

// ---------------- scans (generic, for bucket starts) ----------------

__global__ void scan1_kernel(const int* __restrict__ deg, int* __restrict__ off,
                             int* __restrict__ bsum, int n) {
  __shared__ int sh[256];
  int idx = blockIdx.x * 256 + threadIdx.x;
  int v = (idx < n) ? deg[idx] : 0;
  sh[threadIdx.x] = v;
  __syncthreads();
  for (int d = 1; d < 256; d <<= 1) {
    int x = (threadIdx.x >= (unsigned)d) ? sh[threadIdx.x - d] : 0;
    __syncthreads();
    sh[threadIdx.x] += x;
    __syncthreads();
  }
  if (idx < n) off[idx] = sh[threadIdx.x] - v;   // exclusive
  if (threadIdx.x == 255) bsum[blockIdx.x] = sh[255];
}

__global__ void scan2_kernel(int* __restrict__ bsum, int nb) {
  __shared__ int sh[512];
  int t = threadIdx.x;
  int v = (t < nb) ? bsum[t] : 0;
  sh[t] = v;
  __syncthreads();
  for (int d = 1; d < 512; d <<= 1) {
    int x = (t >= (unsigned)d) ? sh[t - d] : 0;
    __syncthreads();
    sh[t] += x;
    __syncthreads();
  }
  if (t < nb) bsum[t] = sh[t] - v;
}

__global__ void scan3_kernel(int* __restrict__ off, const int* __restrict__ bsum, int n) {
  int idx = blockIdx.x * 256 + threadIdx.x;
  if (idx < n) off[idx] += bsum[blockIdx.x];
}

// ---------------- atomic-free CSR build (counting sort by dst>>7) ----------------
// hist layout TRANSPOSED: hist[bucket * NB + blk]

__global__ __launch_bounds__(256)
void csr_p1(const int* __restrict__ dst, int* __restrict__ hist, int E, int chunk) {
  __shared__ int cnt[NBK];
  const int blk = blockIdx.x, tid = threadIdx.x;
  for (int c = tid; c < NBK; c += 256) cnt[c] = 0;
  __syncthreads();
  int base = blk * chunk;
  int end = base + chunk; if (end > E) end = E;
  for (int e = base + tid; e < end; e += 256) atomicAdd(&cnt[dst[e] >> 7], 1);
  __syncthreads();
  for (int c = tid; c < NBK; c += 256) hist[c * NB + blk] = cnt[c];
}

__global__ __launch_bounds__(256)
void csr_p2(int* __restrict__ hist, int* __restrict__ total) {
  int b = blockIdx.x * 4 + (threadIdx.x >> 6);   // bucket
  int lane = threadIdx.x & 63;
  int4 v = *(int4*)&hist[b * NB + lane * 4];
  int s0 = v.x;
  int s1 = s0 + v.y;
  int s2 = s1 + v.z;
  int s3 = s2 + v.w;
  int t = s3;
  for (int d = 1; d < 64; d <<= 1) {
    int y = __shfl_up(t, d);
    if (lane >= d) t += y;
  }
  int excl = t - s3;
  int4 o;
  o.x = excl; o.y = excl + s0; o.z = excl + s1; o.w = excl + s2;
  *(int4*)&hist[b * NB + lane * 4] = o;
  if (lane == 63) total[b] = t;
}

__global__ __launch_bounds__(256)
void csr_p3(const int* __restrict__ src, const int* __restrict__ dst,
            const int* __restrict__ hist, const int* __restrict__ tstart,
            int* __restrict__ part, int E, int chunk) {
  __shared__ int cur[NBK];
  const int blk = blockIdx.x, tid = threadIdx.x;
  for (int c = tid; c < NBK; c += 256) cur[c] = hist[c * NB + blk] + tstart[c];
  __syncthreads();
  int base = blk * chunk;
  int end = base + chunk; if (end > E) end = E;
  for (int e = base + tid; e < end; e += 256) {
    int d = dst[e];
    int b = d >> 7;
    int pos = atomicAdd(&cur[b], 1);     // LDS atomic
    part[pos] = (src[e] << 7) | (d & 127);
  }
}

__global__ __launch_bounds__(256)
void csr_p4(const int* __restrict__ part, const int* __restrict__ tstart,
            const int* __restrict__ total, int* __restrict__ deg,
            int* __restrict__ off, int* __restrict__ csr, int Nn) {
  __shared__ int lcnt[128], lscan[128], lcur[128];
  const int b = blockIdx.x, tid = threadIdx.x;
  const int p0 = tstart[b];
  const int m = total[b];
  if (tid < 128) lcnt[tid] = 0;
  __syncthreads();
  for (int k = tid; k < m; k += 256) atomicAdd(&lcnt[part[p0 + k] & 127], 1);
  __syncthreads();
  if (tid < 128) lscan[tid] = lcnt[tid];
  __syncthreads();
  for (int d = 1; d < 128; d <<= 1) {
    int v = 0;
    if (tid < 128 && tid >= d) v = lscan[tid - d];
    __syncthreads();
    if (tid < 128) lscan[tid] += v;
    __syncthreads();
  }
  if (tid < 128) {
    int ex = lscan[tid] - lcnt[tid];
    lcur[tid] = ex;
    int n = (b << 7) + tid;
    if (n < Nn) { deg[n] = lcnt[tid]; off[n] = p0 + ex; }
  }
  __syncthreads();
  for (int k = tid; k < m; k += 256) {
    int pk = part[p0 + k];
    int pos = p0 + atomicAdd(&lcur[pk & 127], 1);   // LDS atomic
    csr[pos] = pk >> 7;
  }
}

// ---------------- graph segment offsets via binary search (batch sorted) --------

__global__ void goff_kernel(const int* __restrict__ batch, int* __restrict__ goff,
                            int N, int G) {
  int g = blockIdx.x * 256 + threadIdx.x;
  if (g > G) return;
  if (g == G) { goff[G] = N; return; }
  int lo = 0, hi = N;
  while (lo < hi) { int mid = (lo + hi) >> 1; if (batch[mid] < g) lo = mid + 1; else hi = mid; }
  goff[g] = lo;
}

// ---------------- weight pack -> MFMA FRAGMENT ORDER -----------------------------

__global__ __launch_bounds__(256)
void pack_w_kernel(const float* __restrict__ Wq, const float* __restrict__ Wk,
                   const float* __restrict__ Wv, const float* __restrict__ Ws,
                   const float* __restrict__ bq, const float* __restrict__ bk,
                   const float* __restrict__ bv, const float* __restrict__ bs,
                   __hip_bfloat16* __restrict__ WT2, float* __restrict__ bcat) {
  if (blockIdx.x == 64) {
    for (int c = threadIdx.x; c < 512; c += 256) {
      int which = c >> 7, cc = c & 127;
      const float* b = (which == 0) ? bq : (which == 1) ? bk : (which == 2) ? bv : bs;
      bcat[c] = b[cc];
    }
    return;
  }
  __shared__ float tile[32][33];   // [k-row][c-col]
  const int bid = blockIdx.x;
  const int which = bid >> 4, kb = (bid >> 2) & 3, cb = bid & 3;
  const float* W = (which == 0) ? Wq : (which == 1) ? Wk : (which == 2) ? Wv : Ws;
  const int tx = threadIdx.x & 31, ty = threadIdx.x >> 5;   // ty 0..7
#pragma unroll
  for (int r = ty; r < 32; r += 8)
    tile[r][tx] = W[(kb * 32 + r) * 128 + cb * 32 + tx];
  __syncthreads();
  const int t = threadIdx.x;
  const int mt_sel = t >> 7;            // 0..1
  const int s4 = (t & 127) * 4;
  const int l16 = s4 >> 5;
  const int quad = (s4 >> 3) & 3;
  const int j0 = s4 & 7;
  const int cl = mt_sel * 16 + l16;
  const int kr = quad * 8 + j0;
  float f0 = tile[kr + 0][cl];
  float f1 = tile[kr + 1][cl];
  float f2 = tile[kr + 2][cl];
  float f3 = tile[kr + 3][cl];
  const int mt = which * 8 + cb * 2 + mt_sel;
  const int o = mt * 2048 + kb * 512 + l16 * 32 + quad * 8 + j0;
  uint2 w;
  w.x = pk_bf16(f0, f1);
  w.y = pk_bf16(f2, f3);
  *(uint2*)&((unsigned short*)WT2)[o] = w;
}

// ---------------- fused QKVS GEMM (TRANSPOSED MFMA: D[wcol][node]) ----------------
// 32-ROW tile (R12): xf[2][4] (-32 VGPR), 8.3KB LDS, 2x blocks for latency hiding.
// kvp dword f of node: {k(2f), k(2f+1), v(2f), v(2f+1)} fp8

__global__ __launch_bounds__(256)
void gemm_qkvs(const short* __restrict__ Xb, const short* __restrict__ WT2,
               const float* __restrict__ bc,
               unsigned int* __restrict__ qout,
               unsigned int* __restrict__ kvp,
               unsigned int* __restrict__ xrout, int Nn) {
  __shared__ short As[32][132];   // +4 pad
  const int row0 = blockIdx.x * 32;
  const int tid = threadIdx.x;

#pragma unroll
  for (int p = 0; p < 2; ++p) {
    int chunk = p * 256 + tid;    // 0..511
    int r = chunk >> 4, c8 = chunk & 15;
    int row = row0 + r; if (row >= Nn) row = Nn - 1;
    *(int4*)&As[r][c8 * 8] = *(const int4*)&Xb[(size_t)row * 128 + c8 * 8];
  }
  __syncthreads();

  const int w = tid >> 6, lane = tid & 63, quad = lane >> 4, l16 = lane & 15;

  short8 xf[2][4];
#pragma unroll
  for (int nt = 0; nt < 2; ++nt)
#pragma unroll
    for (int kt = 0; kt < 4; ++kt)
      xf[nt][kt] = *(const short8*)&As[nt * 16 + l16][kt * 32 + quad * 8];

  const int fbase = l16 * 32 + quad * 8;

  if (w == 0 || w == 3) {
    unsigned int* outp = (w == 0) ? qout : xrout;
    const int mbase = (w == 0) ? 0 : 24;
#pragma unroll
    for (int i = 0; i < 8; ++i) {
      const int mt = mbase + i;
      short8 af[4];
#pragma unroll
      for (int kt = 0; kt < 4; ++kt)
        af[kt] = *(const short8*)&WT2[mt * 2048 + kt * 512 + fbase];
      float4 bias = *(const float4*)&bc[mt * 16 + quad * 4];
      const int wc = (i * 16 + quad * 4);
#pragma unroll
      for (int nt = 0; nt < 2; ++nt) {
        floatx4 acc = (floatx4){0.f, 0.f, 0.f, 0.f};
#pragma unroll
        for (int kt = 0; kt < 4; ++kt)
          acc = __builtin_amdgcn_mfma_f32_16x16x32_bf16(af[kt], xf[nt][kt], acc, 0, 0, 0);
        int node = row0 + nt * 16 + l16;
        if (node < Nn) {
          uint2 o;
          o.x = pk_bf16(acc[0] + bias.x, acc[1] + bias.y);
          o.y = pk_bf16(acc[2] + bias.z, acc[3] + bias.w);
          *(uint2*)&outp[(size_t)node * 64 + (wc >> 1)] = o;
        }
      }
    }
  } else {
    const int kb = 8 + (w - 1) * 4;
    const int vb = 16 + (w - 1) * 4;
#pragma unroll
    for (int i = 0; i < 4; ++i) {
      const int mk = kb + i, mv = vb + i;
      short8 afk[4], afv[4];
#pragma unroll
      for (int kt = 0; kt < 4; ++kt) {
        afk[kt] = *(const short8*)&WT2[mk * 2048 + kt * 512 + fbase];
        afv[kt] = *(const short8*)&WT2[mv * 2048 + kt * 512 + fbase];
      }
      float4 bk4 = *(const float4*)&bc[mk * 16 + quad * 4];
      float4 bv4 = *(const float4*)&bc[mv * 16 + quad * 4];
      const int krel = (w - 1) * 64 + i * 16 + quad * 4;
#pragma unroll
      for (int nt = 0; nt < 2; ++nt) {
        floatx4 ak = (floatx4){0.f, 0.f, 0.f, 0.f};
        floatx4 av = (floatx4){0.f, 0.f, 0.f, 0.f};
#pragma unroll
        for (int kt = 0; kt < 4; ++kt) {
          ak = __builtin_amdgcn_mfma_f32_16x16x32_bf16(afk[kt], xf[nt][kt], ak, 0, 0, 0);
          av = __builtin_amdgcn_mfma_f32_16x16x32_bf16(afv[kt], xf[nt][kt], av, 0, 0, 0);
        }
        int node = row0 + nt * 16 + l16;
        if (node < Nn) {
          int d0 = __builtin_amdgcn_cvt_pk_fp8_f32(ak[0] + bk4.x, ak[1] + bk4.y, 0, false);
          d0 = __builtin_amdgcn_cvt_pk_fp8_f32(av[0] + bv4.x, av[1] + bv4.y, d0, true);
          int d1 = __builtin_amdgcn_cvt_pk_fp8_f32(ak[2] + bk4.z, ak[3] + bk4.w, 0, false);
          d1 = __builtin_amdgcn_cvt_pk_fp8_f32(av[2] + bv4.z, av[3] + bv4.w, d1, true);
          uint2 o; o.x = (unsigned)d0; o.y = (unsigned)d1;
          *(uint2*)&kvp[(size_t)node * 64 + (krel >> 1)] = o;
        }
      }
    }
  }
}

// ---------------- attention: one WAVE per node, 32 lanes per edge (R10) ----------

__global__ __launch_bounds__(256)
void attn_kernel(unsigned int* __restrict__ q_h, const uint2* __restrict__ kvp2,
                 const uint2* __restrict__ xr2, const int* __restrict__ off,
                 const int* __restrict__ deg, const int* __restrict__ csr,
                 const float* __restrict__ Wb, int Nn) {
  int wv = __builtin_amdgcn_readfirstlane(threadIdx.x >> 6);
  int i = blockIdx.x * 4 + wv;
  if (i >= Nn) return;
  const int l = threadIdx.x & 63;
  const int j = l & 31;
  const int g = l >> 5;

  const float QS = 0.17677669529663687f * 1.4426950408889634f;  // 1/sqrt(32)*log2e
  uint2 qw = ((const uint2*)q_h)[(size_t)i * 32 + j];
  float q0 = bflo(qw.x) * QS, q1 = bfhi(qw.x) * QS;
  float q2 = bflo(qw.y) * QS, q3 = bfhi(qw.y) * QS;

  const int e0 = off[i];
  const int dg = deg[i];

  float denA = 0.f, aA0 = 0.f, aA1 = 0.f, aA2 = 0.f, aA3 = 0.f;
  float denB = 0.f, aB0 = 0.f, aB1 = 0.f, aB2 = 0.f, aB3 = 0.f;

  auto pair = [&](int s0, int s1, float& den, float& a0, float& a1, float& a2, float& a3) {
    int s = g ? s1 : s0;
    uint2 kv = kvp2[(unsigned)((s << 5) | j)];
    floatx2 k01 = __builtin_amdgcn_cvt_pk_f32_fp8((int)kv.x, false);
    floatx2 v01 = __builtin_amdgcn_cvt_pk_f32_fp8((int)kv.x, true);
    floatx2 k23 = __builtin_amdgcn_cvt_pk_f32_fp8((int)kv.y, false);
    floatx2 v23 = __builtin_amdgcn_cvt_pk_f32_fp8((int)kv.y, true);
    float d = q0 * k01.x + q1 * k01.y + q2 * k23.x + q3 * k23.y;
    d = dpp_add<0xB1>(d);        // quad_perm xor1
    d = dpp_add<0x4E>(d);        // quad_perm xor2
    d += __shfl_xor(d, 4);
    float p = exp2f(d);
    den += p;
    a0 += p * v01.x; a1 += p * v01.y; a2 += p * v23.x; a3 += p * v23.y;
  };

  const int nPair = dg >> 1;
  int e = e0;
  int it = 0;
  for (; it + 1 < nPair; it += 2) {
    int s0 = csr[e], s1 = csr[e + 1], s2 = csr[e + 2], s3 = csr[e + 3];
    pair(s0, s1, denA, aA0, aA1, aA2, aA3);
    pair(s2, s3, denB, aB0, aB1, aB2, aB3);
    e += 4;
  }
  if (it < nPair) {
    int s0 = csr[e], s1 = csr[e + 1];
    pair(s0, s1, denA, aA0, aA1, aA2, aA3);
    e += 2;
  }
  if (dg & 1) {
    int s = csr[e];
    uint2 kv = kvp2[(unsigned)((s << 5) | j)];
    floatx2 k01 = __builtin_amdgcn_cvt_pk_f32_fp8((int)kv.x, false);
    floatx2 v01 = __builtin_amdgcn_cvt_pk_f32_fp8((int)kv.x, true);
    floatx2 k23 = __builtin_amdgcn_cvt_pk_f32_fp8((int)kv.y, false);
    floatx2 v23 = __builtin_amdgcn_cvt_pk_f32_fp8((int)kv.y, true);
    float d = q0 * k01.x + q1 * k01.y + q2 * k23.x + q3 * k23.y;
    d = dpp_add<0xB1>(d);
    d = dpp_add<0x4E>(d);
    d += __shfl_xor(d, 4);
    float p = (g == 0) ? exp2f(d) : 0.f;
    denB += p;
    aB0 += p * v01.x; aB1 += p * v01.y; aB2 += p * v23.x; aB3 += p * v23.y;
  }

  float den = denA + denB;
  float a0 = aA0 + aB0, a1 = aA1 + aB1, a2 = aA2 + aB2, a3 = aA3 + aB3;
  den += __shfl_xor(den, 32);
  a0 += __shfl_xor(a0, 32);
  a1 += __shfl_xor(a1, 32);
  a2 += __shfl_xor(a2, 32);
  a3 += __shfl_xor(a3, 32);
  float inv = 1.f / (den + 1e-16f);
  float o0 = a0 * inv, o1 = a1 * inv, o2 = a2 * inv, o3 = a3 * inv;

  uint2 xw = xr2[(size_t)i * 32 + j];
  float xr0 = bflo(xw.x), xr1 = bfhi(xw.x);
  float xr2v = bflo(xw.y), xr3 = bfhi(xw.y);

  float4 wo = *(const float4*)&Wb[4 * j];
  float4 wx = *(const float4*)&Wb[128 + 4 * j];
  float4 wd = *(const float4*)&Wb[256 + 4 * j];
  float c = o0 * wo.x + o1 * wo.y + o2 * wo.z + o3 * wo.w
          + xr0 * wx.x + xr1 * wx.y + xr2v * wx.z + xr3 * wx.w
          + (o0 - xr0) * wd.x + (o1 - xr1) * wd.y + (o2 - xr2v) * wd.z + (o3 - xr3) * wd.w;
  c += __shfl_xor(c, 1);
  c += __shfl_xor(c, 2);
  c += __shfl_xor(c, 4);
  c += __shfl_xor(c, 8);
  c += __shfl_xor(c, 16);
  float beta = 1.f / (1.f + __expf(-c));

  if (g == 0) {
    float h0 = fmaxf(beta * xr0 + (1.f - beta) * o0, 0.f);
    float h1 = fmaxf(beta * xr1 + (1.f - beta) * o1, 0.f);
    float h2 = fmaxf(beta * xr2v + (1.f - beta) * o2, 0.f);
    float h3 = fmaxf(beta * xr3 + (1.f - beta) * o3, 0.f);
    uint2 hw;
    hw.x = pk_bf16(h0, h1);
    hw.y = pk_bf16(h2, h3);
    ((uint2*)q_h)[(size_t)i * 32 + j] = hw;
  }
}

// ---------------- fused mean-pool + MLP ----------------

__global__ __launch_bounds__(128)
void poolmlp_kernel(const unsigned short* __restrict__ h, const int* __restrict__ goff,
                    const float* __restrict__ W1, const float* __restrict__ b1,
                    const float* __restrict__ W2, const float* __restrict__ b2,
                    const float* __restrict__ W3, const float* __restrict__ b3,
                    float* __restrict__ out) {
  int g = blockIdx.x;
  int t = threadIdx.x;
  int n0 = goff[g], cnt = goff[g + 1] - n0;
  float s = 0.f;
  for (int n = n0; n < n0 + cnt; ++n) s += bflo(h[(size_t)n * 128 + t]);
  __shared__ float gv[128];
  __shared__ float t1[64];
  __shared__ float t2[32];
  gv[t] = s / fmaxf((float)cnt, 1.0f);
  __syncthreads();
  if (t < 64) {
    float a = b1[t];
    for (int k = 0; k < 128; ++k) a += gv[k] * W1[k * 64 + t];
    t1[t] = fmaxf(a, 0.f);
  }
  __syncthreads();
  if (t < 32) {
    float a = b2[t];
    for (int k = 0; k < 64; ++k) a += t1[k] * W2[k * 32 + t];
    t2[t] = fmaxf(a, 0.f);
  }
  __syncthreads();
  if (t == 0) {
    float a = b3[0];
    for (int k = 0; k < 32; ++k) a += t2[k] * W3[k];
    out[g] = 1.f / (1.f + __expf(-a));
  }
}

// ---------------- launch ----------------

extern "C" void kernel_launch(void* const* d_in, const int* in_sizes, int n_in,
                              void* d_out, int out_size, void* d_ws, size_t ws_size,
                              hipStream_t stream) {
  const float* x = (const float*)d_in[0];
  const int* edge_index = (const int*)d_in[1];
  const int* batch = (const int*)d_in[2];
  const int N = in_sizes[0] / DH;
  const int E = in_sizes[1] / 2;
  const int G = out_size;
  const int* src = edge_index;
  const int* dst = edge_index + E;

  const float* in_Wq = (const float*)d_in[3];
  const float* in_bq = (const float*)d_in[4];
  const float* in_Wk = (const float*)d_in[5];
  const float* in_bk = (const float*)d_in[6];
  const float* in_Wv = (const float*)d_in[7];
  const float* in_bv = (const float*)d_in[8];
  const float* in_Ws = (const float*)d_in[9];
  const float* in_bs = (const float*)d_in[10];
  const float* in_Wbeta = (const float*)d_in[11];
  const float* blk_Wq = (const float*)d_in[12];
  const float* blk_bq = (const float*)d_in[13];
  const float* blk_Wk = (const float*)d_in[14];
  const float* blk_bk = (const float*)d_in[15];
  const float* blk_Wv = (const float*)d_in[16];
  const float* blk_bv = (const float*)d_in[17];
  const float* blk_Ws = (const float*)d_in[18];
  const float* blk_bs = (const float*)d_in[19];
  const float* blk_Wbeta = (const float*)d_in[20];

  // workspace carve (256B aligned)
  char* p = (char*)d_ws;
  auto take = [&](size_t bytes) { char* r = p; p += (bytes + 255) & ~(size_t)255; return r; };
  __hip_bfloat16* h0 = (__hip_bfloat16*)take((size_t)N * DH * 2);
  __hip_bfloat16* h1 = (__hip_bfloat16*)take((size_t)N * DH * 2);
  unsigned char* kvp = (unsigned char*)take((size_t)N * 256);
  unsigned short* xr = (unsigned short*)take((size_t)N * DH * 2);
  __hip_bfloat16* WT2 = (__hip_bfloat16*)take((size_t)512 * DH * 2);
  float* bcat = (float*)take(512 * 4);
  int* deg    = (int*)take((size_t)N * 4);
  int* off    = (int*)take((size_t)N * 4);
  int* csr    = (int*)take((size_t)E * 4);
  int* part   = (int*)take((size_t)E * 4);
  int* hist   = (int*)take((size_t)NB * NBK * 4);
  int* total  = (int*)take(NBK * 4);
  int* tstart = (int*)take(NBK * 4);
  int* bsumP  = (int*)take(512 * 4);
  int* goff   = (int*)take((size_t)(G + 1) * 4);
  (void)n_in;
  if ((size_t)(p - (char*)d_ws) > ws_size) return;

  const int NBUCK = (N + 127) >> 7;
  const int chunk = (E + NB - 1) / NB;

  // ---- atomic-free CSR build ----
  csr_p1<<<NB, 256, 0, stream>>>(dst, hist, E, chunk);
  csr_p2<<<NBK / 4, 256, 0, stream>>>(hist, total);
  scan1_kernel<<<NBK / 256, 256, 0, stream>>>(total, tstart, bsumP, NBK);
  scan2_kernel<<<1, 512, 0, stream>>>(bsumP, NBK / 256);
  scan3_kernel<<<NBK / 256, 256, 0, stream>>>(tstart, bsumP, NBK);
  csr_p3<<<NB, 256, 0, stream>>>(src, dst, hist, tstart, part, E, chunk);
  csr_p4<<<NBUCK, 256, 0, stream>>>(part, tstart, total, deg, off, csr, N);

  // ---- graph segment offsets (batch sorted) ----
  goff_kernel<<<(G + 256) / 256, 256, 0, stream>>>(batch, goff, N, G);

  cvt_bf16<<<(int)(((size_t)N * DH + 255) / 256), 256, 0, stream>>>(x, h0, N * DH);

  for (int l = 0; l < 4; ++l) {
    const float *Wq, *Wk, *Wv, *Ws, *bq, *bk, *bv, *bs, *Wb;
    if (l == 0) {
      Wq = in_Wq; Wk = in_Wk; Wv = in_Wv; Ws = in_Ws;
      bq = in_bq; bk = in_bk; bv = in_bv; bs = in_bs; Wb = in_Wbeta;
    } else {
      int m = l - 1;
      Wq = blk_Wq + (size_t)m * DH * DH; Wk = blk_Wk + (size_t)m * DH * DH;
      Wv = blk_Wv + (size_t)m * DH * DH; Ws = blk_Ws + (size_t)m * DH * DH;
      bq = blk_bq + (size_t)m * DH; bk = blk_bk + (size_t)m * DH;
      bv = blk_bv + (size_t)m * DH; bs = blk_bs + (size_t)m * DH;
      Wb = blk_Wbeta + (size_t)m * 3 * DH;
    }
    __hip_bfloat16* hin  = (l & 1) ? h1 : h0;
    __hip_bfloat16* qbuf = (l & 1) ? h0 : h1;
    pack_w_kernel<<<65, 256, 0, stream>>>(Wq, Wk, Wv, Ws, bq, bk, bv, bs, WT2, bcat);
    gemm_qkvs<<<(N + 31) / 32, 256, 0, stream>>>((const short*)hin, (const short*)WT2, bcat,
        (unsigned int*)qbuf, (unsigned int*)kvp, (unsigned int*)xr, N);
    attn_kernel<<<(N + 3) / 4, 256, 0, stream>>>((unsigned int*)qbuf, (const uint2*)kvp,
        (const uint2*)xr, off, deg, csr, Wb, N);
  }

  // after 4 layers h lives in h0
  poolmlp_kernel<<<G, 128, 0, stream>>>((const unsigned short*)h0, goff,
      (const float*)d_in[21], (const float*)d_in[22],
      (const float*)d_in[23], (const float*)d_in[24],
      (const float*)d_in[25], (const float*)d_in[26],
      (float*)d_out);
}